// Round 3
// baseline (427.476 us; speedup 1.0000x reference)
//
#include <hip/hip_runtime.h>
#include <math.h>

// GNN message-passing layer — linearity restructure + bf16 MFMA + ILP'd gather.
//   agg[r] = (sum x_snd) @ Wm_x^T + (sum e_attr) @ Wm_e^T   (message fn is linear)
// Pipeline:
//   memset counts
//   prep:  Wcat=[W1a | W1b@Wm]->bf16, W2/Wn->bf16, nodes->bf16, hist(receivers)
//   scan1/2/3: parallel exclusive scan -> row_ptr, cursor
//   build: CSR ps[pos] = {sender, edge}  (single int2 store: 1 random 8B line
//          per edge instead of 2 independent random 4B stores)
//   aggsum: S[r] = [sum nodes_bf[snd] | sum eattr] -> bf16
//           (wave/receiver, 64-entry int2 shfl-prefetch, 4-edge unroll)
//   node_fused: h = LN(relu([nodes_bf|S] @ Wcat^T + b1))         (h stays in LDS)
//               out = LN(nodes_bf @ Wn^T + LN(relu(h @ W2^T + b2)))
//     GEMM chunks use 2-phase register prefetch: next chunk's A/B global loads
//     issue right after the stage barrier, overlapping MFMA of current chunk.
// GEMMs: bf16 LDS tiles -> v_mfma_f32_16x16x32_bf16.
// Block tile M=64 x N=128, BK=32, 4 waves 2x2, each wave 32x64 (2x4 16x16 tiles).

#define THREADS 256
#define BM 64
#define BK 32
#define APB 40   // LDS row pitch in bf16 (80B rows -> <=2-way bank alias, free)
#define BP 132   // Cs row pitch (floats)

typedef __attribute__((ext_vector_type(8))) short bf16x8;
typedef __attribute__((ext_vector_type(4))) float f32x4;

struct GemmSmem {
  unsigned short As[BM][APB];
  unsigned short Bs[128][APB];
};
struct EpiSmem {
  float Cs[BM][BP];
  float psum[BM][4];
  float psq[BM][4];
  float mu[BM];
  float rs[BM];
};

union BF8 { bf16x8 v; ushort4 q[2]; };

__device__ __forceinline__ unsigned short f2bf(float x) {
  union { float f; unsigned u; } c; c.f = x;
  unsigned u = c.u;
  u += 0x7fffu + ((u >> 16) & 1u);   // RNE
  return (unsigned short)(u >> 16);
}
__device__ __forceinline__ float bf2f(unsigned h) {
  union { unsigned u; float f; } c; c.u = h << 16; return c.f;
}
__device__ __forceinline__ ushort4 cvt4(float4 v) {
  ushort4 p; p.x = f2bf(v.x); p.y = f2bf(v.y); p.z = f2bf(v.z); p.w = f2bf(v.w);
  return p;
}

// ---------------- prep: weight fold/convert + nodes->bf16 + receiver histogram ----
__global__ __launch_bounds__(256) void prep_kernel(
    const float* __restrict__ W1, const float* __restrict__ Wm,
    const float* __restrict__ W2, const float* __restrict__ Wn,
    const float* __restrict__ nodes, const int* __restrict__ eidx,
    unsigned short* __restrict__ Wcat, unsigned short* __restrict__ W2b,
    unsigned short* __restrict__ Wnb, unsigned short* __restrict__ nodes_bf,
    int* __restrict__ counts, int Nn, int E, int nconv) {
  const int b = blockIdx.x, tid = threadIdx.x;
  if (b < 128) {
    for (int t = tid; t < 288; t += 256) {
      float v;
      if (t < 128) {
        v = W1[(size_t)b * 256 + t];
      } else {
        int u = t - 128;
        float s = 0.f;
#pragma unroll 8
        for (int k = 0; k < 128; ++k)
          s += W1[(size_t)b * 256 + 128 + k] * Wm[(size_t)k * 160 + u];
        v = s;
      }
      Wcat[(size_t)b * 288 + t] = f2bf(v);
    }
  } else if (b < 144) {
    int idx = (b - 128) * 1024 + tid * 4;
    *(ushort4*)&W2b[idx] = cvt4(*(const float4*)&W2[idx]);
  } else if (b < 160) {
    int idx = (b - 144) * 1024 + tid * 4;
    *(ushort4*)&Wnb[idx] = cvt4(*(const float4*)&Wn[idx]);
  } else if (b < 160 + nconv) {
    int idx = ((b - 160) * 256 + tid) * 4;
    if (idx < Nn * 128)
      *(ushort4*)&nodes_bf[idx] = cvt4(*(const float4*)&nodes[idx]);
  } else {
    int i = (b - 160 - nconv) * 256 + tid;
    if (i < E) atomicAdd(&counts[eidx[E + i]], 1);
  }
}

// ---------------- parallel exclusive scan over counts ----------------
__global__ __launch_bounds__(256) void scan1_kernel(const int* __restrict__ counts,
                                                    int* __restrict__ bsum, int Nn) {
  __shared__ int red[256];
  const int tid = threadIdx.x;
  int base = blockIdx.x * 2048 + tid * 8;
  int s = 0;
#pragma unroll
  for (int i = 0; i < 8; ++i) {
    int idx = base + i;
    if (idx < Nn) s += counts[idx];
  }
  red[tid] = s;
  __syncthreads();
#pragma unroll
  for (int off = 128; off; off >>= 1) {
    if (tid < off) red[tid] += red[tid + off];
    __syncthreads();
  }
  if (tid == 0) bsum[blockIdx.x] = red[0];
}

__global__ __launch_bounds__(256) void scan2_kernel(const int* __restrict__ bsum,
                                                    int* __restrict__ boff, int NB) {
  __shared__ int arr[256];
  const int tid = threadIdx.x;
  int v = (tid < NB) ? bsum[tid] : 0;
  arr[tid] = v;
  __syncthreads();
  for (int off = 1; off < 256; off <<= 1) {
    int t2 = (tid >= off) ? arr[tid - off] : 0;
    __syncthreads();
    arr[tid] += t2;
    __syncthreads();
  }
  if (tid < NB) boff[tid] = arr[tid] - v;   // exclusive
}

__global__ __launch_bounds__(256) void scan3_kernel(const int* __restrict__ counts,
                                                    const int* __restrict__ boff,
                                                    int* __restrict__ row_ptr,
                                                    int* __restrict__ cursor, int Nn) {
  __shared__ int arr[256];
  const int tid = threadIdx.x;
  int base = blockIdx.x * 2048 + tid * 8;
  int c[8];
  int s = 0;
#pragma unroll
  for (int i = 0; i < 8; ++i) {
    int idx = base + i;
    c[i] = (idx < Nn) ? counts[idx] : 0;
    s += c[i];
  }
  arr[tid] = s;
  __syncthreads();
  for (int off = 1; off < 256; off <<= 1) {
    int t2 = (tid >= off) ? arr[tid - off] : 0;
    __syncthreads();
    arr[tid] += t2;
    __syncthreads();
  }
  int run = arr[tid] - s + boff[blockIdx.x];
#pragma unroll
  for (int i = 0; i < 8; ++i) {
    int idx = base + i;
    if (idx < Nn) {
      row_ptr[idx] = run;
      cursor[idx] = run;
    }
    run += c[i];
  }
}

__global__ __launch_bounds__(256) void build_kernel(const int* __restrict__ eidx,
                                                    int* __restrict__ cursor,
                                                    int2* __restrict__ ps, int E) {
  int i = blockIdx.x * 256 + threadIdx.x;
  if (i < E) {
    int r = eidx[E + i];
    int pos = atomicAdd(&cursor[r], 1);
    ps[pos] = make_int2(eidx[i], i);   // {sender, edge id} — one 8B line
  }
}

// ------- per-receiver input sums: shfl-prefetched indices, 4-edge unroll --------
__global__ __launch_bounds__(256) void aggsum_kernel(
    const unsigned short* __restrict__ nodes_bf, const float* __restrict__ eattr,
    const int* __restrict__ row_ptr, const int* __restrict__ rend,
    const int2* __restrict__ ps, unsigned short* __restrict__ S, int Nn) {
  const int wid = blockIdx.x * 4 + (threadIdx.x >> 6);
  if (wid >= Nn) return;
  const int lane = threadIdx.x & 63;
  const int start = row_ptr[wid];
  const int end = rend[wid];
  const int deg = end - start;
  const int dmax = deg < 64 ? deg : 64;

  // one coalesced int2 load grabs up to 64 CSR entries for this receiver
  int sv = 0, pv = 0;
  if (lane < deg) {
    int2 sp = ps[start + lane];
    sv = sp.x;
    pv = sp.y;
  }

  const unsigned* nodes32 = (const unsigned*)nodes_bf;
  const int rsub = lane >> 5;   // half-wave: which of 2 eattr rows per load
  const int col = lane & 31;
  float s0 = 0.f, s1 = 0.f, seA = 0.f, seB = 0.f;

  int t = 0;
  for (; t + 4 <= dmax; t += 4) {
    int i0 = __shfl(sv, t + 0);
    int i1 = __shfl(sv, t + 1);
    int i2 = __shfl(sv, t + 2);
    int i3 = __shfl(sv, t + 3);
    int pA = __shfl(pv, t + rsub);
    int pB = __shfl(pv, t + 2 + rsub);
    unsigned a0 = nodes32[(size_t)i0 * 64 + lane];
    unsigned a1 = nodes32[(size_t)i1 * 64 + lane];
    unsigned a2 = nodes32[(size_t)i2 * 64 + lane];
    unsigned a3 = nodes32[(size_t)i3 * 64 + lane];
    float vA = eattr[(size_t)pA * 32 + col];
    float vB = eattr[(size_t)pB * 32 + col];
    s0 += bf2f(a0 & 0xffffu) + bf2f(a1 & 0xffffu) +
          bf2f(a2 & 0xffffu) + bf2f(a3 & 0xffffu);
    s1 += bf2f(a0 >> 16) + bf2f(a1 >> 16) + bf2f(a2 >> 16) + bf2f(a3 >> 16);
    seA += vA;
    seB += vB;
  }
  for (; t < dmax; ++t) {
    int i0 = __shfl(sv, t);
    int p = __shfl(pv, t);
    unsigned a0 = nodes32[(size_t)i0 * 64 + lane];
    s0 += bf2f(a0 & 0xffffu);
    s1 += bf2f(a0 >> 16);
    if (rsub == 0) seA += eattr[(size_t)p * 32 + col];
  }
  // overflow path (deg > 64) — rare, wave-uniform
  for (int j = start + 64; j < end; ++j) {
    int2 sp = ps[j];
    unsigned a = nodes32[(size_t)sp.x * 64 + lane];
    s0 += bf2f(a & 0xffffu);
    s1 += bf2f(a >> 16);
    if (rsub == 0) seA += eattr[(size_t)sp.y * 32 + col];
  }

  // eattr: combine interleaved rows, then halves
  float se = seA + seB;
  se += __shfl_xor(se, 32);

  unsigned pack = (unsigned)f2bf(s0) | ((unsigned)f2bf(s1) << 16);
  ((unsigned*)S)[(size_t)wid * 80 + lane] = pack;

  float lo = __shfl(se, 2 * (lane & 15));
  float hi = __shfl(se, 2 * (lane & 15) + 1);
  if (lane < 16) {
    unsigned p2 = (unsigned)f2bf(lo) | ((unsigned)f2bf(hi) << 16);
    ((unsigned*)S)[(size_t)wid * 80 + 64 + lane] = p2;
  }
}

// ---------------- shared GEMM pieces ----------------
__device__ __forceinline__ void gemm_chunk(const GemmSmem& sm, int tid,
                                           f32x4 acc[2][4]) {
  const int lane = tid & 63;
  const int quad = lane >> 4;
  const int lm = lane & 15;
  const int wid = tid >> 6;
  const int wy = wid >> 1, wx = wid & 1;

  bf16x8 af[2], bf[4];
#pragma unroll
  for (int mt = 0; mt < 2; ++mt)
    af[mt] = *(const bf16x8*)&sm.As[32 * wy + 16 * mt + lm][quad * 8];
#pragma unroll
  for (int nt = 0; nt < 4; ++nt)
    bf[nt] = *(const bf16x8*)&sm.Bs[64 * wx + 16 * nt + lm][quad * 8];
#pragma unroll
  for (int mt = 0; mt < 2; ++mt)
#pragma unroll
    for (int nt = 0; nt < 4; ++nt)
      acc[mt][nt] = __builtin_amdgcn_mfma_f32_16x16x32_bf16(
          af[mt], bf[nt], acc[mt][nt], 0, 0, 0);
}

// register-staging helpers (2-phase prefetch building blocks)
__device__ __forceinline__ void stage_A(const unsigned short* __restrict__ A,
                                        int row0, int Nn, int kc, int tid, BF8& ta) {
  int r = tid >> 2, u = tid & 3;
  int row = row0 + r;
  if (row >= Nn) row = Nn - 1;
  ta.v = *(const bf16x8*)&A[(size_t)row * 128 + kc + 8 * u];
}
__device__ __forceinline__ void stage_A_cat(const unsigned short* __restrict__ A0,
                                            const unsigned short* __restrict__ A1,
                                            int row0, int Nn, int kc, int tid,
                                            BF8& ta) {
  int r = tid >> 2, u = tid & 3;
  int k = kc + 8 * u;
  int row = row0 + r;
  if (row >= Nn) row = Nn - 1;
  if (kc >= 128)
    ta.v = *(const bf16x8*)&A1[(size_t)row * 160 + (k - 128)];
  else
    ta.v = *(const bf16x8*)&A0[(size_t)row * 128 + k];
}
__device__ __forceinline__ void stage_B(const unsigned short* __restrict__ W,
                                        int ldw, int kc, int tid, BF8 tb[2]) {
#pragma unroll
  for (int c = 0; c < 2; ++c) {
    int f = tid + 256 * c;
    int n = f >> 2, u = f & 3;
    tb[c].v = *(const bf16x8*)&W[(size_t)n * ldw + kc + 8 * u];
  }
}
__device__ __forceinline__ void write_A(GemmSmem& g, int tid, const BF8& ta) {
  int r = tid >> 2, u = tid & 3;
  *(ushort4*)&g.As[r][8 * u] = ta.q[0];
  *(ushort4*)&g.As[r][8 * u + 4] = ta.q[1];
}
__device__ __forceinline__ void write_B(GemmSmem& g, int tid, const BF8 tb[2]) {
#pragma unroll
  for (int c = 0; c < 2; ++c) {
    int f = tid + 256 * c;
    int n = f >> 2, u = f & 3;
    *(ushort4*)&g.Bs[n][8 * u] = tb[c].q[0];
    *(ushort4*)&g.Bs[n][8 * u + 4] = tb[c].q[1];
  }
}

// K=128 GEMM, A from global bf16 rows, 2-phase register prefetch
__device__ __forceinline__ void gemm_k128(const unsigned short* __restrict__ A,
                                          const unsigned short* __restrict__ W,
                                          int row0, int Nn, GemmSmem& g, int tid,
                                          f32x4 acc[2][4]) {
  BF8 ta, tb[2], na, nb[2];
  stage_A(A, row0, Nn, 0, tid, ta);
  stage_B(W, 128, 0, tid, tb);
  for (int kc = 0; kc < 128; kc += BK) {
    write_A(g, tid, ta);
    write_B(g, tid, tb);
    __syncthreads();
    if (kc + BK < 128) {
      stage_A(A, row0, Nn, kc + BK, tid, na);
      stage_B(W, 128, kc + BK, tid, nb);
    }
    gemm_chunk(g, tid, acc);
    __syncthreads();
    ta = na;
    tb[0] = nb[0];
    tb[1] = nb[1];
  }
}

// K=128 GEMM, A from the f32 Cs tile in LDS (RNE convert at staging — identical
// rounding to a bf16 global round-trip), B prefetched from global
__device__ __forceinline__ void gemm_k128_lds(const EpiSmem& e,
                                              const unsigned short* __restrict__ W,
                                              GemmSmem& g, int tid,
                                              f32x4 acc[2][4]) {
  BF8 tb[2], nb[2];
  stage_B(W, 128, 0, tid, tb);
  for (int kc = 0; kc < 128; kc += BK) {
    {
      int r = tid >> 2, u = tid & 3;
      float4 lo = *(const float4*)&e.Cs[r][kc + 8 * u];
      float4 hi = *(const float4*)&e.Cs[r][kc + 8 * u + 4];
      *(ushort4*)&g.As[r][8 * u] = cvt4(lo);
      *(ushort4*)&g.As[r][8 * u + 4] = cvt4(hi);
    }
    write_B(g, tid, tb);
    __syncthreads();
    if (kc + BK < 128) stage_B(W, 128, kc + BK, tid, nb);
    gemm_chunk(g, tid, acc);
    __syncthreads();
    tb[0] = nb[0];
    tb[1] = nb[1];
  }
}

__device__ __forceinline__ void ln_stats(EpiSmem& e, int tid) {
  {
    int q = tid & 3, r = tid >> 2;
    float s = 0.f, s2 = 0.f;
#pragma unroll 8
    for (int j = q * 32; j < q * 32 + 32; ++j) {
      float x = e.Cs[r][j];
      s += x;
      s2 += x * x;
    }
    e.psum[r][q] = s;
    e.psq[r][q] = s2;
  }
  __syncthreads();
  if (tid < BM) {
    float S_ = 0.f, S2 = 0.f;
#pragma unroll
    for (int q = 0; q < 4; ++q) {
      S_ += e.psum[tid][q];
      S2 += e.psq[tid][q];
    }
    float m = S_ * (1.f / 128.f);
    float var = S2 * (1.f / 128.f) - m * m;
    e.mu[tid] = m;
    e.rs[tid] = rsqrtf(var + 1e-5f);
  }
  __syncthreads();
}

// ---- fused node pipeline: per 64-row tile ----
//   phase A: h = LN1(relu([nodes|S] @ Wcat^T + b1))  (K=288) -> Cs (f32)
//   phase B: t = LN2(relu(h @ W2^T + b2))            (A from Cs in LDS) -> Cs
//   phase C: out = LNf(nodes @ Wn^T + t)             (K=128)
__global__ __launch_bounds__(THREADS, 3) void node_fused_kernel(
    const unsigned short* __restrict__ A0, const unsigned short* __restrict__ A1,
    const unsigned short* __restrict__ Wcat, const float* __restrict__ b1,
    const float* __restrict__ g1, const float* __restrict__ bl1,
    const unsigned short* __restrict__ W2b, const unsigned short* __restrict__ Wnb,
    const float* __restrict__ b2, const float* __restrict__ g2,
    const float* __restrict__ bl2, const float* __restrict__ gf,
    const float* __restrict__ blf, float* __restrict__ out, int Nn) {
  __shared__ GemmSmem g;
  __shared__ EpiSmem e;
  const int tid = threadIdx.x;
  const int row0 = blockIdx.x * BM;
  const int lane = tid & 63;
  const int quad = lane >> 4;
  const int lm = lane & 15;
  const int wid = tid >> 6;
  const int wy = wid >> 1, wx = wid & 1;

  f32x4 acc[2][4];
#pragma unroll
  for (int mt = 0; mt < 2; ++mt)
#pragma unroll
    for (int nt = 0; nt < 4; ++nt) acc[mt][nt] = (f32x4)0.f;

  // ---- phase A: [nodes|S] @ Wcat^T (K=288), 2-phase register prefetch ----
  {
    BF8 ta, tb[2], na, nb[2];
    stage_A_cat(A0, A1, row0, Nn, 0, tid, ta);
    stage_B(Wcat, 288, 0, tid, tb);
    for (int kc = 0; kc < 288; kc += BK) {
      write_A(g, tid, ta);
      write_B(g, tid, tb);
      __syncthreads();
      if (kc + BK < 288) {
        stage_A_cat(A0, A1, row0, Nn, kc + BK, tid, na);
        stage_B(Wcat, 288, kc + BK, tid, nb);
      }
      gemm_chunk(g, tid, acc);
      __syncthreads();
      ta = na;
      tb[0] = nb[0];
      tb[1] = nb[1];
    }
  }

  // epilogue A: relu + b1 -> Cs, LN1, normalize in place (h, f32)
  {
    float bval[4];
#pragma unroll
    for (int nt = 0; nt < 4; ++nt) bval[nt] = b1[64 * wx + 16 * nt + lm];
#pragma unroll
    for (int mt = 0; mt < 2; ++mt)
#pragma unroll
      for (int i = 0; i < 4; ++i) {
        int r = 32 * wy + 16 * mt + quad * 4 + i;
#pragma unroll
        for (int nt = 0; nt < 4; ++nt) {
          int col = 64 * wx + 16 * nt + lm;
          e.Cs[r][col] = fmaxf(acc[mt][nt][i] + bval[nt], 0.f);
        }
      }
  }
  __syncthreads();
  ln_stats(e, tid);
#pragma unroll 4
  for (int s = 0; s < 32; ++s) {
    int flat = tid + THREADS * s;
    int r = flat >> 7, j = flat & 127;
    float x = e.Cs[r][j];
    e.Cs[r][j] = (x - e.mu[r]) * e.rs[r] * g1[j] + bl1[j];
  }
  __syncthreads();

  // ---- phase B: h @ W2^T (A from LDS), relu+b2, LN2 -> Cs (node_out tile) ----
#pragma unroll
  for (int mt = 0; mt < 2; ++mt)
#pragma unroll
    for (int nt = 0; nt < 4; ++nt) acc[mt][nt] = (f32x4)0.f;

  gemm_k128_lds(e, W2b, g, tid, acc);

  {
    float bval[4];
#pragma unroll
    for (int nt = 0; nt < 4; ++nt) bval[nt] = b2[64 * wx + 16 * nt + lm];
#pragma unroll
    for (int mt = 0; mt < 2; ++mt)
#pragma unroll
      for (int i = 0; i < 4; ++i) {
        int r = 32 * wy + 16 * mt + quad * 4 + i;
#pragma unroll
        for (int nt = 0; nt < 4; ++nt) {
          int col = 64 * wx + 16 * nt + lm;
          e.Cs[r][col] = fmaxf(acc[mt][nt][i] + bval[nt], 0.f);
        }
      }
  }
  __syncthreads();
  ln_stats(e, tid);
#pragma unroll 4
  for (int s = 0; s < 32; ++s) {
    int flat = tid + THREADS * s;
    int r = flat >> 7, j = flat & 127;
    float x = e.Cs[r][j];
    e.Cs[r][j] = (x - e.mu[r]) * e.rs[r] * g2[j] + bl2[j];
  }
  __syncthreads();

  // ---- phase C: nodes @ Wn^T + node_out, final LN ----
#pragma unroll
  for (int mt = 0; mt < 2; ++mt)
#pragma unroll
    for (int nt = 0; nt < 4; ++nt) acc[mt][nt] = (f32x4)0.f;

  gemm_k128(A0, Wnb, row0, Nn, g, tid, acc);

#pragma unroll
  for (int mt = 0; mt < 2; ++mt)
#pragma unroll
    for (int i = 0; i < 4; ++i) {
      int r = 32 * wy + 16 * mt + quad * 4 + i;
#pragma unroll
      for (int nt = 0; nt < 4; ++nt) {
        int col = 64 * wx + 16 * nt + lm;
        e.Cs[r][col] = acc[mt][nt][i] + e.Cs[r][col];
      }
    }
  __syncthreads();
  ln_stats(e, tid);

#pragma unroll 4
  for (int s = 0; s < 32; ++s) {
    int flat = tid + THREADS * s;
    int r = flat >> 7, j = flat & 127;
    int row = row0 + r;
    if (row < Nn) {
      float x = e.Cs[r][j];
      out[(size_t)row * 128 + j] =
          (x - e.mu[r]) * e.rs[r] * gf[j] + blf[j];
    }
  }
}

extern "C" void kernel_launch(void* const* d_in, const int* in_sizes, int n_in,
                              void* d_out, int out_size, void* d_ws, size_t ws_size,
                              hipStream_t stream) {
  const float* nodes = (const float*)d_in[0];
  const int* eidx    = (const int*)d_in[1];
  const float* eattr = (const float*)d_in[2];
  const float* Wm    = (const float*)d_in[3];
  const float* Wn    = (const float*)d_in[4];
  const float* W1    = (const float*)d_in[5];
  const float* b1    = (const float*)d_in[6];
  const float* g1    = (const float*)d_in[7];
  const float* bl1   = (const float*)d_in[8];
  const float* W2    = (const float*)d_in[9];
  const float* b2    = (const float*)d_in[10];
  const float* g2    = (const float*)d_in[11];
  const float* bl2   = (const float*)d_in[12];
  const float* gf    = (const float*)d_in[13];
  const float* blf   = (const float*)d_in[14];
  float* out = (float*)d_out;

  const int Nn = in_sizes[0] / 128;   // 100000
  const int E  = in_sizes[2] / 32;    // 800000

  // workspace layout (all 16B-aligned)
  int* counts  = (int*)d_ws;                       // [Nn]
  int* row_ptr = counts + Nn;                      // [Nn]
  int* cursor  = row_ptr + Nn;                     // [Nn] (segment ends after build)
  int* bsum    = cursor + Nn;                      // [256]
  int* boff    = bsum + 256;                       // [256]
  int2* ps     = (int2*)(boff + 256);              // [E] {sender, edge}
  unsigned short* Wcat     = (unsigned short*)((int*)ps + 2 * (size_t)E);  // [128*288]
  unsigned short* W2b      = Wcat + 128 * 288;                  // [128*128]
  unsigned short* Wnb      = W2b + 128 * 128;                   // [128*128]
  unsigned short* nodes_bf = Wnb + 128 * 128;                   // [Nn*128]
  unsigned short* S_bf     = nodes_bf + (size_t)Nn * 128;       // [Nn*160]

  hipMemsetAsync(counts, 0, (size_t)Nn * sizeof(int), stream);

  const int nconv = (Nn * 32 + 255) / 256;   // nodes float4 chunks
  const int nhist = (E + 255) / 256;
  const int NB = (Nn + 2047) / 2048;
  const int ngrid = (Nn + BM - 1) / BM;

  prep_kernel<<<160 + nconv + nhist, 256, 0, stream>>>(
      W1, Wm, W2, Wn, nodes, eidx, Wcat, W2b, Wnb, nodes_bf, counts, Nn, E, nconv);
  scan1_kernel<<<NB, 256, 0, stream>>>(counts, bsum, Nn);
  scan2_kernel<<<1, 256, 0, stream>>>(bsum, boff, NB);
  scan3_kernel<<<NB, 256, 0, stream>>>(counts, boff, row_ptr, cursor, Nn);
  build_kernel<<<nhist, 256, 0, stream>>>(eidx, cursor, ps, E);
  aggsum_kernel<<<(Nn + 3) / 4, 256, 0, stream>>>(nodes_bf, eattr, row_ptr, cursor,
                                                  ps, S_bf, Nn);
  node_fused_kernel<<<ngrid, THREADS, 0, stream>>>(
      nodes_bf, S_bf, Wcat, b1, g1, bl1, W2b, Wnb, b2, g2, bl2, gf, blf, out, Nn);
}

// Round 4
// 420.760 us; speedup vs baseline: 1.0160x; 1.0160x over previous
//
#include <hip/hip_runtime.h>
#include <math.h>

// GNN message-passing layer — linearity restructure + bf16 MFMA + ILP'd gather.
//   agg[r] = (sum x_snd) @ Wm_x^T + (sum e_attr) @ Wm_e^T   (message fn is linear)
// Pipeline:
//   memset counts
//   prep:  Wcat=[W1a | W1b@Wm]->bf16, W2/Wn->bf16, nodes->bf16, hist(receivers)
//   scan1/2/3: parallel exclusive scan -> row_ptr, cursor
//   build: CSR ps[pos] = {sender, edge}  (single int2 store)
//   aggsum: S[r] = [sum nodes_bf[snd] | sum eattr] -> bf16
//           (wave/receiver; 8-edge full-issue chunks: 8 node loads via
//            readlane/SGPR-base + 4 eattr loads all in flight before any
//            accumulation -> one gather round for deg<=8 receivers)
//   node_fused: h = LN(relu([nodes_bf|S] @ Wcat^T + b1))         (h stays in LDS)
//               out = LN(nodes_bf @ Wn^T + LN(relu(h @ W2^T + b2)))
//     GEMM chunks use 2-phase register prefetch.
// GEMMs: bf16 LDS tiles -> v_mfma_f32_16x16x32_bf16.
// Block tile M=64 x N=128, BK=32, 4 waves 2x2, each wave 32x64 (2x4 16x16 tiles).

#define THREADS 256
#define BM 64
#define BK 32
#define APB 40   // LDS row pitch in bf16 (80B rows -> <=2-way bank alias, free)
#define BP 132   // Cs row pitch (floats)

typedef __attribute__((ext_vector_type(8))) short bf16x8;
typedef __attribute__((ext_vector_type(4))) float f32x4;

struct GemmSmem {
  unsigned short As[BM][APB];
  unsigned short Bs[128][APB];
};
struct EpiSmem {
  float Cs[BM][BP];
  float psum[BM][4];
  float psq[BM][4];
  float mu[BM];
  float rs[BM];
};

union BF8 { bf16x8 v; ushort4 q[2]; };

__device__ __forceinline__ unsigned short f2bf(float x) {
  union { float f; unsigned u; } c; c.f = x;
  unsigned u = c.u;
  u += 0x7fffu + ((u >> 16) & 1u);   // RNE
  return (unsigned short)(u >> 16);
}
__device__ __forceinline__ float bf2f(unsigned h) {
  union { unsigned u; float f; } c; c.u = h << 16; return c.f;
}
__device__ __forceinline__ ushort4 cvt4(float4 v) {
  ushort4 p; p.x = f2bf(v.x); p.y = f2bf(v.y); p.z = f2bf(v.z); p.w = f2bf(v.w);
  return p;
}

// ---------------- prep: weight fold/convert + nodes->bf16 + receiver histogram ----
__global__ __launch_bounds__(256) void prep_kernel(
    const float* __restrict__ W1, const float* __restrict__ Wm,
    const float* __restrict__ W2, const float* __restrict__ Wn,
    const float* __restrict__ nodes, const int* __restrict__ eidx,
    unsigned short* __restrict__ Wcat, unsigned short* __restrict__ W2b,
    unsigned short* __restrict__ Wnb, unsigned short* __restrict__ nodes_bf,
    int* __restrict__ counts, int Nn, int E, int nconv) {
  const int b = blockIdx.x, tid = threadIdx.x;
  if (b < 128) {
    for (int t = tid; t < 288; t += 256) {
      float v;
      if (t < 128) {
        v = W1[(size_t)b * 256 + t];
      } else {
        int u = t - 128;
        float s = 0.f;
#pragma unroll 8
        for (int k = 0; k < 128; ++k)
          s += W1[(size_t)b * 256 + 128 + k] * Wm[(size_t)k * 160 + u];
        v = s;
      }
      Wcat[(size_t)b * 288 + t] = f2bf(v);
    }
  } else if (b < 144) {
    int idx = (b - 128) * 1024 + tid * 4;
    *(ushort4*)&W2b[idx] = cvt4(*(const float4*)&W2[idx]);
  } else if (b < 160) {
    int idx = (b - 144) * 1024 + tid * 4;
    *(ushort4*)&Wnb[idx] = cvt4(*(const float4*)&Wn[idx]);
  } else if (b < 160 + nconv) {
    int idx = ((b - 160) * 256 + tid) * 4;
    if (idx < Nn * 128)
      *(ushort4*)&nodes_bf[idx] = cvt4(*(const float4*)&nodes[idx]);
  } else {
    int i = (b - 160 - nconv) * 256 + tid;
    if (i < E) atomicAdd(&counts[eidx[E + i]], 1);
  }
}

// ---------------- parallel exclusive scan over counts ----------------
__global__ __launch_bounds__(256) void scan1_kernel(const int* __restrict__ counts,
                                                    int* __restrict__ bsum, int Nn) {
  __shared__ int red[256];
  const int tid = threadIdx.x;
  int base = blockIdx.x * 2048 + tid * 8;
  int s = 0;
#pragma unroll
  for (int i = 0; i < 8; ++i) {
    int idx = base + i;
    if (idx < Nn) s += counts[idx];
  }
  red[tid] = s;
  __syncthreads();
#pragma unroll
  for (int off = 128; off; off >>= 1) {
    if (tid < off) red[tid] += red[tid + off];
    __syncthreads();
  }
  if (tid == 0) bsum[blockIdx.x] = red[0];
}

__global__ __launch_bounds__(256) void scan2_kernel(const int* __restrict__ bsum,
                                                    int* __restrict__ boff, int NB) {
  __shared__ int arr[256];
  const int tid = threadIdx.x;
  int v = (tid < NB) ? bsum[tid] : 0;
  arr[tid] = v;
  __syncthreads();
  for (int off = 1; off < 256; off <<= 1) {
    int t2 = (tid >= off) ? arr[tid - off] : 0;
    __syncthreads();
    arr[tid] += t2;
    __syncthreads();
  }
  if (tid < NB) boff[tid] = arr[tid] - v;   // exclusive
}

__global__ __launch_bounds__(256) void scan3_kernel(const int* __restrict__ counts,
                                                    const int* __restrict__ boff,
                                                    int* __restrict__ row_ptr,
                                                    int* __restrict__ cursor, int Nn) {
  __shared__ int arr[256];
  const int tid = threadIdx.x;
  int base = blockIdx.x * 2048 + tid * 8;
  int c[8];
  int s = 0;
#pragma unroll
  for (int i = 0; i < 8; ++i) {
    int idx = base + i;
    c[i] = (idx < Nn) ? counts[idx] : 0;
    s += c[i];
  }
  arr[tid] = s;
  __syncthreads();
  for (int off = 1; off < 256; off <<= 1) {
    int t2 = (tid >= off) ? arr[tid - off] : 0;
    __syncthreads();
    arr[tid] += t2;
    __syncthreads();
  }
  int run = arr[tid] - s + boff[blockIdx.x];
#pragma unroll
  for (int i = 0; i < 8; ++i) {
    int idx = base + i;
    if (idx < Nn) {
      row_ptr[idx] = run;
      cursor[idx] = run;
    }
    run += c[i];
  }
}

__global__ __launch_bounds__(256) void build_kernel(const int* __restrict__ eidx,
                                                    int* __restrict__ cursor,
                                                    int2* __restrict__ ps, int E) {
  int i = blockIdx.x * 256 + threadIdx.x;
  if (i < E) {
    int r = eidx[E + i];
    int pos = atomicAdd(&cursor[r], 1);
    ps[pos] = make_int2(eidx[i], i);   // {sender, edge id} — one 8B line
  }
}

// ------- per-receiver input sums: 8-edge full-issue chunks ----------------------
// Per chunk: 8 node-row loads (readlane -> SGPR base, no per-load VGPR addr math)
// + 4 eattr loads (2 rows per load via half-wave rsub) ALL issued before any
// accumulation -> 12 loads in flight, one gather round for deg<=8.
__global__ __launch_bounds__(256) void aggsum_kernel(
    const unsigned short* __restrict__ nodes_bf, const float* __restrict__ eattr,
    const int* __restrict__ row_ptr, const int* __restrict__ rend,
    const int2* __restrict__ ps, unsigned short* __restrict__ S, int Nn) {
  const int wid = blockIdx.x * 4 + (threadIdx.x >> 6);
  if (wid >= Nn) return;
  const int lane = threadIdx.x & 63;
  const int start = row_ptr[wid];
  const int end = rend[wid];
  const int deg = end - start;
  const int dmax = deg < 64 ? deg : 64;

  // one coalesced int2 load grabs up to 64 CSR entries for this receiver
  int sv = 0, pv = 0;
  if (lane < deg) {
    int2 sp = ps[start + lane];
    sv = sp.x;
    pv = sp.y;
  }

  const unsigned* nodes32 = (const unsigned*)nodes_bf;
  const int rsub = lane >> 5;   // half-wave: which of 2 eattr rows per load
  const int col = lane & 31;
  float s0 = 0.f, s1 = 0.f, se = 0.f;

  for (int t0 = 0; t0 < dmax; t0 += 8) {
    unsigned a[8];
    float ev[4];
    // issue all 8 node gathers (clamped index -> harmless L1-hit duplicates)
#pragma unroll
    for (int k = 0; k < 8; ++k) {
      int tt = t0 + k;
      if (tt > dmax - 1) tt = dmax - 1;
      int idx = __builtin_amdgcn_readlane(sv, tt);   // wave-uniform -> SGPR
      a[k] = nodes32[(size_t)idx * 64 + lane];
    }
    // issue all 4 eattr gathers (index differs by half-wave -> shfl)
#pragma unroll
    for (int k = 0; k < 4; ++k) {
      int tt = t0 + 2 * k + rsub;
      if (tt > dmax - 1) tt = dmax - 1;
      int p = __shfl(pv, tt);
      ev[k] = eattr[(size_t)p * 32 + col];
    }
    // accumulate (wave-uniform masks on nodes, per-lane cndmask on eattr)
#pragma unroll
    for (int k = 0; k < 8; ++k) {
      if (t0 + k < dmax) {
        s0 += bf2f(a[k] & 0xffffu);
        s1 += bf2f(a[k] >> 16);
      }
    }
#pragma unroll
    for (int k = 0; k < 4; ++k) {
      se += (t0 + 2 * k + rsub < dmax) ? ev[k] : 0.f;
    }
  }

  // overflow path (deg > 64) — rare, wave-uniform
  for (int j = start + 64; j < end; ++j) {
    int2 sp = ps[j];
    unsigned a = nodes32[(size_t)sp.x * 64 + lane];
    s0 += bf2f(a & 0xffffu);
    s1 += bf2f(a >> 16);
    if (rsub == 0) se += eattr[(size_t)sp.y * 32 + col];
  }

  // eattr: combine halves (lanes rsub=0 hold even edges, rsub=1 odd)
  se += __shfl_xor(se, 32);

  unsigned pack = (unsigned)f2bf(s0) | ((unsigned)f2bf(s1) << 16);
  ((unsigned*)S)[(size_t)wid * 80 + lane] = pack;

  float lo = __shfl(se, 2 * (lane & 15));
  float hi = __shfl(se, 2 * (lane & 15) + 1);
  if (lane < 16) {
    unsigned p2 = (unsigned)f2bf(lo) | ((unsigned)f2bf(hi) << 16);
    ((unsigned*)S)[(size_t)wid * 80 + 64 + lane] = p2;
  }
}

// ---------------- shared GEMM pieces ----------------
__device__ __forceinline__ void gemm_chunk(const GemmSmem& sm, int tid,
                                           f32x4 acc[2][4]) {
  const int lane = tid & 63;
  const int quad = lane >> 4;
  const int lm = lane & 15;
  const int wid = tid >> 6;
  const int wy = wid >> 1, wx = wid & 1;

  bf16x8 af[2], bf[4];
#pragma unroll
  for (int mt = 0; mt < 2; ++mt)
    af[mt] = *(const bf16x8*)&sm.As[32 * wy + 16 * mt + lm][quad * 8];
#pragma unroll
  for (int nt = 0; nt < 4; ++nt)
    bf[nt] = *(const bf16x8*)&sm.Bs[64 * wx + 16 * nt + lm][quad * 8];
#pragma unroll
  for (int mt = 0; mt < 2; ++mt)
#pragma unroll
    for (int nt = 0; nt < 4; ++nt)
      acc[mt][nt] = __builtin_amdgcn_mfma_f32_16x16x32_bf16(
          af[mt], bf[nt], acc[mt][nt], 0, 0, 0);
}

// register-staging helpers (2-phase prefetch building blocks)
__device__ __forceinline__ void stage_A(const unsigned short* __restrict__ A,
                                        int row0, int Nn, int kc, int tid, BF8& ta) {
  int r = tid >> 2, u = tid & 3;
  int row = row0 + r;
  if (row >= Nn) row = Nn - 1;
  ta.v = *(const bf16x8*)&A[(size_t)row * 128 + kc + 8 * u];
}
__device__ __forceinline__ void stage_A_cat(const unsigned short* __restrict__ A0,
                                            const unsigned short* __restrict__ A1,
                                            int row0, int Nn, int kc, int tid,
                                            BF8& ta) {
  int r = tid >> 2, u = tid & 3;
  int k = kc + 8 * u;
  int row = row0 + r;
  if (row >= Nn) row = Nn - 1;
  if (kc >= 128)
    ta.v = *(const bf16x8*)&A1[(size_t)row * 160 + (k - 128)];
  else
    ta.v = *(const bf16x8*)&A0[(size_t)row * 128 + k];
}
__device__ __forceinline__ void stage_B(const unsigned short* __restrict__ W,
                                        int ldw, int kc, int tid, BF8 tb[2]) {
#pragma unroll
  for (int c = 0; c < 2; ++c) {
    int f = tid + 256 * c;
    int n = f >> 2, u = f & 3;
    tb[c].v = *(const bf16x8*)&W[(size_t)n * ldw + kc + 8 * u];
  }
}
__device__ __forceinline__ void write_A(GemmSmem& g, int tid, const BF8& ta) {
  int r = tid >> 2, u = tid & 3;
  *(ushort4*)&g.As[r][8 * u] = ta.q[0];
  *(ushort4*)&g.As[r][8 * u + 4] = ta.q[1];
}
__device__ __forceinline__ void write_B(GemmSmem& g, int tid, const BF8 tb[2]) {
#pragma unroll
  for (int c = 0; c < 2; ++c) {
    int f = tid + 256 * c;
    int n = f >> 2, u = f & 3;
    *(ushort4*)&g.Bs[n][8 * u] = tb[c].q[0];
    *(ushort4*)&g.Bs[n][8 * u + 4] = tb[c].q[1];
  }
}

// K=128 GEMM, A from global bf16 rows, 2-phase register prefetch
__device__ __forceinline__ void gemm_k128(const unsigned short* __restrict__ A,
                                          const unsigned short* __restrict__ W,
                                          int row0, int Nn, GemmSmem& g, int tid,
                                          f32x4 acc[2][4]) {
  BF8 ta, tb[2], na, nb[2];
  stage_A(A, row0, Nn, 0, tid, ta);
  stage_B(W, 128, 0, tid, tb);
  for (int kc = 0; kc < 128; kc += BK) {
    write_A(g, tid, ta);
    write_B(g, tid, tb);
    __syncthreads();
    if (kc + BK < 128) {
      stage_A(A, row0, Nn, kc + BK, tid, na);
      stage_B(W, 128, kc + BK, tid, nb);
    }
    gemm_chunk(g, tid, acc);
    __syncthreads();
    ta = na;
    tb[0] = nb[0];
    tb[1] = nb[1];
  }
}

// K=128 GEMM, A from the f32 Cs tile in LDS (RNE convert at staging — identical
// rounding to a bf16 global round-trip), B prefetched from global
__device__ __forceinline__ void gemm_k128_lds(const EpiSmem& e,
                                              const unsigned short* __restrict__ W,
                                              GemmSmem& g, int tid,
                                              f32x4 acc[2][4]) {
  BF8 tb[2], nb[2];
  stage_B(W, 128, 0, tid, tb);
  for (int kc = 0; kc < 128; kc += BK) {
    {
      int r = tid >> 2, u = tid & 3;
      float4 lo = *(const float4*)&e.Cs[r][kc + 8 * u];
      float4 hi = *(const float4*)&e.Cs[r][kc + 8 * u + 4];
      *(ushort4*)&g.As[r][8 * u] = cvt4(lo);
      *(ushort4*)&g.As[r][8 * u + 4] = cvt4(hi);
    }
    write_B(g, tid, tb);
    __syncthreads();
    if (kc + BK < 128) stage_B(W, 128, kc + BK, tid, nb);
    gemm_chunk(g, tid, acc);
    __syncthreads();
    tb[0] = nb[0];
    tb[1] = nb[1];
  }
}

__device__ __forceinline__ void ln_stats(EpiSmem& e, int tid) {
  {
    int q = tid & 3, r = tid >> 2;
    float s = 0.f, s2 = 0.f;
#pragma unroll 8
    for (int j = q * 32; j < q * 32 + 32; ++j) {
      float x = e.Cs[r][j];
      s += x;
      s2 += x * x;
    }
    e.psum[r][q] = s;
    e.psq[r][q] = s2;
  }
  __syncthreads();
  if (tid < BM) {
    float S_ = 0.f, S2 = 0.f;
#pragma unroll
    for (int q = 0; q < 4; ++q) {
      S_ += e.psum[tid][q];
      S2 += e.psq[tid][q];
    }
    float m = S_ * (1.f / 128.f);
    float var = S2 * (1.f / 128.f) - m * m;
    e.mu[tid] = m;
    e.rs[tid] = rsqrtf(var + 1e-5f);
  }
  __syncthreads();
}

// ---- fused node pipeline: per 64-row tile ----
//   phase A: h = LN1(relu([nodes|S] @ Wcat^T + b1))  (K=288) -> Cs (f32)
//   phase B: t = LN2(relu(h @ W2^T + b2))            (A from Cs in LDS) -> Cs
//   phase C: out = LNf(nodes @ Wn^T + t)             (K=128)
__global__ __launch_bounds__(THREADS, 3) void node_fused_kernel(
    const unsigned short* __restrict__ A0, const unsigned short* __restrict__ A1,
    const unsigned short* __restrict__ Wcat, const float* __restrict__ b1,
    const float* __restrict__ g1, const float* __restrict__ bl1,
    const unsigned short* __restrict__ W2b, const unsigned short* __restrict__ Wnb,
    const float* __restrict__ b2, const float* __restrict__ g2,
    const float* __restrict__ bl2, const float* __restrict__ gf,
    const float* __restrict__ blf, float* __restrict__ out, int Nn) {
  __shared__ GemmSmem g;
  __shared__ EpiSmem e;
  const int tid = threadIdx.x;
  const int row0 = blockIdx.x * BM;
  const int lane = tid & 63;
  const int quad = lane >> 4;
  const int lm = lane & 15;
  const int wid = tid >> 6;
  const int wy = wid >> 1, wx = wid & 1;

  f32x4 acc[2][4];
#pragma unroll
  for (int mt = 0; mt < 2; ++mt)
#pragma unroll
    for (int nt = 0; nt < 4; ++nt) acc[mt][nt] = (f32x4)0.f;

  // ---- phase A: [nodes|S] @ Wcat^T (K=288), 2-phase register prefetch ----
  {
    BF8 ta, tb[2], na, nb[2];
    stage_A_cat(A0, A1, row0, Nn, 0, tid, ta);
    stage_B(Wcat, 288, 0, tid, tb);
    for (int kc = 0; kc < 288; kc += BK) {
      write_A(g, tid, ta);
      write_B(g, tid, tb);
      __syncthreads();
      if (kc + BK < 288) {
        stage_A_cat(A0, A1, row0, Nn, kc + BK, tid, na);
        stage_B(Wcat, 288, kc + BK, tid, nb);
      }
      gemm_chunk(g, tid, acc);
      __syncthreads();
      ta = na;
      tb[0] = nb[0];
      tb[1] = nb[1];
    }
  }

  // epilogue A: relu + b1 -> Cs, LN1, normalize in place (h, f32)
  {
    float bval[4];
#pragma unroll
    for (int nt = 0; nt < 4; ++nt) bval[nt] = b1[64 * wx + 16 * nt + lm];
#pragma unroll
    for (int mt = 0; mt < 2; ++mt)
#pragma unroll
      for (int i = 0; i < 4; ++i) {
        int r = 32 * wy + 16 * mt + quad * 4 + i;
#pragma unroll
        for (int nt = 0; nt < 4; ++nt) {
          int col = 64 * wx + 16 * nt + lm;
          e.Cs[r][col] = fmaxf(acc[mt][nt][i] + bval[nt], 0.f);
        }
      }
  }
  __syncthreads();
  ln_stats(e, tid);
#pragma unroll 4
  for (int s = 0; s < 32; ++s) {
    int flat = tid + THREADS * s;
    int r = flat >> 7, j = flat & 127;
    float x = e.Cs[r][j];
    e.Cs[r][j] = (x - e.mu[r]) * e.rs[r] * g1[j] + bl1[j];
  }
  __syncthreads();

  // ---- phase B: h @ W2^T (A from LDS), relu+b2, LN2 -> Cs (node_out tile) ----
#pragma unroll
  for (int mt = 0; mt < 2; ++mt)
#pragma unroll
    for (int nt = 0; nt < 4; ++nt) acc[mt][nt] = (f32x4)0.f;

  gemm_k128_lds(e, W2b, g, tid, acc);

  {
    float bval[4];
#pragma unroll
    for (int nt = 0; nt < 4; ++nt) bval[nt] = b2[64 * wx + 16 * nt + lm];
#pragma unroll
    for (int mt = 0; mt < 2; ++mt)
#pragma unroll
      for (int i = 0; i < 4; ++i) {
        int r = 32 * wy + 16 * mt + quad * 4 + i;
#pragma unroll
        for (int nt = 0; nt < 4; ++nt) {
          int col = 64 * wx + 16 * nt + lm;
          e.Cs[r][col] = fmaxf(acc[mt][nt][i] + bval[nt], 0.f);
        }
      }
  }
  __syncthreads();
  ln_stats(e, tid);
#pragma unroll 4
  for (int s = 0; s < 32; ++s) {
    int flat = tid + THREADS * s;
    int r = flat >> 7, j = flat & 127;
    float x = e.Cs[r][j];
    e.Cs[r][j] = (x - e.mu[r]) * e.rs[r] * g2[j] + bl2[j];
  }
  __syncthreads();

  // ---- phase C: nodes @ Wn^T + node_out, final LN ----
#pragma unroll
  for (int mt = 0; mt < 2; ++mt)
#pragma unroll
    for (int nt = 0; nt < 4; ++nt) acc[mt][nt] = (f32x4)0.f;

  gemm_k128(A0, Wnb, row0, Nn, g, tid, acc);

#pragma unroll
  for (int mt = 0; mt < 2; ++mt)
#pragma unroll
    for (int i = 0; i < 4; ++i) {
      int r = 32 * wy + 16 * mt + quad * 4 + i;
#pragma unroll
      for (int nt = 0; nt < 4; ++nt) {
        int col = 64 * wx + 16 * nt + lm;
        e.Cs[r][col] = acc[mt][nt][i] + e.Cs[r][col];
      }
    }
  __syncthreads();
  ln_stats(e, tid);

#pragma unroll 4
  for (int s = 0; s < 32; ++s) {
    int flat = tid + THREADS * s;
    int r = flat >> 7, j = flat & 127;
    int row = row0 + r;
    if (row < Nn) {
      float x = e.Cs[r][j];
      out[(size_t)row * 128 + j] =
          (x - e.mu[r]) * e.rs[r] * gf[j] + blf[j];
    }
  }
}

extern "C" void kernel_launch(void* const* d_in, const int* in_sizes, int n_in,
                              void* d_out, int out_size, void* d_ws, size_t ws_size,
                              hipStream_t stream) {
  const float* nodes = (const float*)d_in[0];
  const int* eidx    = (const int*)d_in[1];
  const float* eattr = (const float*)d_in[2];
  const float* Wm    = (const float*)d_in[3];
  const float* Wn    = (const float*)d_in[4];
  const float* W1    = (const float*)d_in[5];
  const float* b1    = (const float*)d_in[6];
  const float* g1    = (const float*)d_in[7];
  const float* bl1   = (const float*)d_in[8];
  const float* W2    = (const float*)d_in[9];
  const float* b2    = (const float*)d_in[10];
  const float* g2    = (const float*)d_in[11];
  const float* bl2   = (const float*)d_in[12];
  const float* gf    = (const float*)d_in[13];
  const float* blf   = (const float*)d_in[14];
  float* out = (float*)d_out;

  const int Nn = in_sizes[0] / 128;   // 100000
  const int E  = in_sizes[2] / 32;    // 800000

  // workspace layout (all 16B-aligned)
  int* counts  = (int*)d_ws;                       // [Nn]
  int* row_ptr = counts + Nn;                      // [Nn]
  int* cursor  = row_ptr + Nn;                     // [Nn] (segment ends after build)
  int* bsum    = cursor + Nn;                      // [256]
  int* boff    = bsum + 256;                       // [256]
  int2* ps     = (int2*)(boff + 256);              // [E] {sender, edge}
  unsigned short* Wcat     = (unsigned short*)((int*)ps + 2 * (size_t)E);  // [128*288]
  unsigned short* W2b      = Wcat + 128 * 288;                  // [128*128]
  unsigned short* Wnb      = W2b + 128 * 128;                   // [128*128]
  unsigned short* nodes_bf = Wnb + 128 * 128;                   // [Nn*128]
  unsigned short* S_bf     = nodes_bf + (size_t)Nn * 128;       // [Nn*160]

  hipMemsetAsync(counts, 0, (size_t)Nn * sizeof(int), stream);

  const int nconv = (Nn * 32 + 255) / 256;   // nodes float4 chunks
  const int nhist = (E + 255) / 256;
  const int NB = (Nn + 2047) / 2048;
  const int ngrid = (Nn + BM - 1) / BM;

  prep_kernel<<<160 + nconv + nhist, 256, 0, stream>>>(
      W1, Wm, W2, Wn, nodes, eidx, Wcat, W2b, Wnb, nodes_bf, counts, Nn, E, nconv);
  scan1_kernel<<<NB, 256, 0, stream>>>(counts, bsum, Nn);
  scan2_kernel<<<1, 256, 0, stream>>>(bsum, boff, NB);
  scan3_kernel<<<NB, 256, 0, stream>>>(counts, boff, row_ptr, cursor, Nn);
  build_kernel<<<nhist, 256, 0, stream>>>(eidx, cursor, ps, E);
  aggsum_kernel<<<(Nn + 3) / 4, 256, 0, stream>>>(nodes_bf, eattr, row_ptr, cursor,
                                                  ps, S_bf, Nn);
  node_fused_kernel<<<ngrid, THREADS, 0, stream>>>(
      nodes_bf, S_bf, Wcat, b1, g1, bl1, W2b, Wnb, b2, g2, bl2, gf, blf, out, Nn);
}